// Round 5
// baseline (607.826 us; speedup 1.0000x reference)
//
#include <hip/hip_runtime.h>
#include <stdint.h>

#define OUT_F 4096
#define IN_F  4096
#define MROWS 8192            // 4*2048
#define NTILE (IN_F / 64)     // 64 K-tiles of 64

typedef __attribute__((ext_vector_type(8)))  short shortx8;   // 8 bf16 = 4 VGPRs
typedef __attribute__((ext_vector_type(16))) float floatx16;  // 32x32 C/D = 16 AGPRs

// fp32 -> bf16 bits, round-to-nearest-even
__device__ __forceinline__ unsigned short f32_to_bf16(float f) {
    unsigned int u = __builtin_bit_cast(unsigned int, f);
    u += 0x7FFFu + ((u >> 16) & 1u);
    return (unsigned short)(u >> 16);
}

// ---------------- preprocessing (unchanged from R4) ----------------
#define XQUADS (MROWS * IN_F / 4)
#define WQUADS (OUT_F * IN_F / 4)
#define PRE_XBLK 4096
#define PRE_WBLK 2048
__global__ void __launch_bounds__(256)
preprocess_kernel(const float* __restrict__ x, short* __restrict__ xb,
                  const int* __restrict__ q, const float* __restrict__ s,
                  short* __restrict__ wb) {
    const int b = blockIdx.x;
    if (b < PRE_XBLK) {
        const float4* xi = (const float4*)x;
        ushort4*      xo = (ushort4*)xb;
        for (int i = b * 256 + (int)threadIdx.x; i < XQUADS; i += PRE_XBLK * 256) {
            float4 v = xi[i];
            ushort4 o;
            o.x = f32_to_bf16(v.x); o.y = f32_to_bf16(v.y);
            o.z = f32_to_bf16(v.z); o.w = f32_to_bf16(v.w);
            xo[i] = o;
        }
    } else {
        const int4* qi = (const int4*)q;
        ushort4*    wo = (ushort4*)wb;
        for (int i = (b - PRE_XBLK) * 256 + (int)threadIdx.x; i < WQUADS; i += PRE_WBLK * 256) {
            int4 a = qi[i];
            float sc = s[i >> 4];
            ushort4 o;
            o.x = f32_to_bf16((float)a.x * sc); o.y = f32_to_bf16((float)a.y * sc);
            o.z = f32_to_bf16((float)a.z * sc); o.w = f32_to_bf16((float)a.w * sc);
            wo[i] = o;
        }
    }
}

// ---------------- 256x256 8-phase GEMM, v_mfma_f32_32x32x16_bf16 ----------------
// C[M,N] = A[M,K]*B[N,K]^T + bias.  BM=BN=256, BK=64, 8 waves (2M x 4N),
// per-wave output 128x64 = 4 m-frags x 2 n-frags of 32x32.  K-tile = 4 ksteps of 16.
// LDS layout / staging / swizzle / vmcnt ledger IDENTICAL to the verified R3/R4
// kernel.  Only the fragment shape changed (16x16x32 -> 32x32x16):
//   A-frag(f,c): lane l holds row l&31 of rows [wm*128+f*32, +32), k = c*16+(l>>5)*8+j
//   B-frag(nf,c): same pattern on B rows (wn*64+nf*32)
//   C/D: col = lane&31, row = (reg&3)+8*(reg>>2)+4*(lane>>5)   [m74/m101]
// Read volume unchanged (A 16 + B 8 reads of b128 per wave-tile); MFMA count
// halves (32/tile/wave) on the 15%-faster 32x32 pipe (m06/m119: 2382-2495 vs
// 2075-2176 TF).
//
// Phase schedule (tile t in CUR, t+1 in NXT) — same read->unit mapping as R3:
//   P1: VMC(8);  BAR; ST U3(t+1)->NXT; rd bn1(t)<-U2(t);  Q(m01,n0);        BAR
//   P2: VMC(8);  BAR; ST U0(t+2)->CUR; Q(m01,n1) || rd af<-m23(t)=U3(t);    BAR
//   P3: VMC(6);  BAR; ST U1(t+2)->CUR; Q(m23,n0) || rd bn0(t+1)<-U1(t+1);   BAR
//   P4: VMC(10); BAR; ST U2(t+2)->CUR; Q(m23,n1) || rd af<-m01(t+1)=U0(t+1);BAR
// All four vmcnt landing proofs carry over verbatim (same units, same phases).

#define BAR()  asm volatile("s_barrier" ::: "memory")
#define VMC(n) asm volatile("s_waitcnt vmcnt(" #n ")" ::: "memory")
#define SGB(mask, n) __builtin_amdgcn_sched_group_barrier((mask), (n), 0)

#define GLD(gp, lo) __builtin_amdgcn_global_load_lds( \
    (const __attribute__((address_space(1))) uint32_t*)(gp), \
    (__attribute__((address_space(3))) uint32_t*)(smem + (lo)), 16, 0, 0)

#define ST_U0(d, BO) do { GLD(gA + (d)*64,            (BO) + lbA        ); \
                          GLD(gA + (d)*64 + 128*IN_F, (BO) + lbA + 16384); } while (0)
#define ST_U3(d, BO) do { GLD(gA + (d)*64 +  64*IN_F, (BO) + lbA +  8192); \
                          GLD(gA + (d)*64 + 192*IN_F, (BO) + lbA + 24576); } while (0)
#define ST_U1(d, BO) do { GLD(gB + (d)*64,            (BO) + lbB        ); \
                          GLD(gB + (d)*64 + 128*IN_F, (BO) + lbB + 16384); } while (0)
#define ST_U2(d, BO) do { GLD(gB + (d)*64 +  32*IN_F, (BO) + lbB +  4096); \
                          GLD(gB + (d)*64 + 160*IN_F, (BO) + lbB + 20480); } while (0)

// fragment reads: per-lane base aAddr[c]/bAddr[c] + compile-time frag offset
#define LDA32(F, C, BO)  (*(const shortx8*)(smem + (BO) + aAddr[C] + (F)*4096))
#define LDB32(NF, C, BO) (*(const shortx8*)(smem + (BO) + bAddr[C] + (NF)*4096))

#define RD_BN0(BO)  do { _Pragma("unroll") \
    for (int c_ = 0; c_ < 4; ++c_) bn0[c_] = LDB32(0, c_, BO); } while (0)
#define RD_BN1(BO)  do { _Pragma("unroll") \
    for (int c_ = 0; c_ < 4; ++c_) bn1[c_] = LDB32(1, c_, BO); } while (0)
#define RD_AF01(BO) do { _Pragma("unroll") \
    for (int c_ = 0; c_ < 4; ++c_) { af[0][c_] = LDA32(0, c_, BO); af[1][c_] = LDA32(1, c_, BO); } } while (0)
#define RD_AF23(BO) do { _Pragma("unroll") \
    for (int c_ = 0; c_ < 4; ++c_) { af[0][c_] = LDA32(2, c_, BO); af[1][c_] = LDA32(3, c_, BO); } } while (0)

#define MFMA32(AF, BF, ACC) \
    ACC = __builtin_amdgcn_mfma_f32_32x32x16_bf16((AF), (BF), (ACC), 0, 0, 0)

// one C-quadrant x K=64: 8 MFMAs, c-outer/f-inner (dep distance 2 per acc)
#define QUAD(MB, NF, BB) do { __builtin_amdgcn_s_setprio(1); \
    _Pragma("unroll") for (int c_ = 0; c_ < 4; ++c_) \
      _Pragma("unroll") for (int f_ = 0; f_ < 2; ++f_) \
        MFMA32(af[f_][c_], BB[c_], acc[(MB)+f_][NF]); \
    __builtin_amdgcn_s_setprio(0); } while (0)

#define PH1(CUR,NXT,dN) do { VMC(8); BAR(); ST_U3(dN,NXT); RD_BN1(CUR); \
    QUAD(0, 0, bn0); \
    SGB(0x100,4); SGB(0x8,8); \
    BAR(); } while (0)

// Q(m01,n1) interleaved with af<-m23(CUR): reload af[f][c] right after its use
#define PH2(CUR,dNN) do { VMC(8); BAR(); ST_U0(dNN,CUR); \
    __builtin_amdgcn_s_setprio(1); \
    _Pragma("unroll") for (int c_ = 0; c_ < 4; ++c_) { \
        MFMA32(af[0][c_], bn1[c_], acc[0][1]); \
        MFMA32(af[1][c_], bn1[c_], acc[1][1]); \
        af[0][c_] = LDA32(2, c_, CUR); af[1][c_] = LDA32(3, c_, CUR); } \
    __builtin_amdgcn_s_setprio(0); \
    SGB(0x8,2); SGB(0x100,2); SGB(0x8,2); SGB(0x100,2); \
    SGB(0x8,2); SGB(0x100,2); SGB(0x8,2); SGB(0x100,2); \
    BAR(); } while (0)

// Q(m23,n0) interleaved with bn0(t+1)<-NXT
#define PH3(CUR,NXT,dNN) do { VMC(6); BAR(); ST_U1(dNN,CUR); \
    __builtin_amdgcn_s_setprio(1); \
    _Pragma("unroll") for (int c_ = 0; c_ < 4; ++c_) { \
        MFMA32(af[0][c_], bn0[c_], acc[2][0]); \
        MFMA32(af[1][c_], bn0[c_], acc[3][0]); \
        bn0[c_] = LDB32(0, c_, NXT); } \
    __builtin_amdgcn_s_setprio(0); \
    SGB(0x8,2); SGB(0x100,1); SGB(0x8,2); SGB(0x100,1); \
    SGB(0x8,2); SGB(0x100,1); SGB(0x8,2); SGB(0x100,1); \
    BAR(); } while (0)

// Q(m23,n1) interleaved with af<-m01(t+1)<-NXT
#define PH4(CUR,NXT,dNN) do { VMC(10); BAR(); ST_U2(dNN,CUR); \
    __builtin_amdgcn_s_setprio(1); \
    _Pragma("unroll") for (int c_ = 0; c_ < 4; ++c_) { \
        MFMA32(af[0][c_], bn1[c_], acc[2][1]); \
        MFMA32(af[1][c_], bn1[c_], acc[3][1]); \
        af[0][c_] = LDA32(0, c_, NXT); af[1][c_] = LDA32(1, c_, NXT); } \
    __builtin_amdgcn_s_setprio(0); \
    SGB(0x8,2); SGB(0x100,2); SGB(0x8,2); SGB(0x100,2); \
    SGB(0x8,2); SGB(0x100,2); SGB(0x8,2); SGB(0x100,2); \
    BAR(); } while (0)

__global__ void __launch_bounds__(512, 2)
gemm_bf16_8phase(const short* __restrict__ A, const short* __restrict__ B,
                 const float* __restrict__ bias, float* __restrict__ C) {
    __shared__ __align__(16) char smem[131072];   // [buf][A 32K | B 32K]

    const int tid  = threadIdx.x;
    const int w    = tid >> 6;        // wave 0..7
    const int lane = tid & 63;
    const int wm   = w >> 2;          // 0..1
    const int wn   = w & 3;           // 0..3

    // T1: XCD-aware swizzle (512 wgs, 512%8==0 -> bijective)
    const int bid  = blockIdx.x;
    const int swz  = ((bid & 7) << 6) | (bid >> 3);
    const int row0 = (swz >> 4) << 8;   // M tile * 256
    const int col0 = (swz & 15) << 8;   // N tile * 256

    // ---- staging: per-lane pre-swizzled global src, wave-uniform linear LDS dest ----
    const int lrow = lane >> 3;
    const int lch  = (lane & 7) ^ lrow;
    const short* gA = A + (int64_t)(row0 + w * 8 + lrow) * IN_F + lch * 8;
    const int bb   = w * 8 + (w >> 2) * 32;
    const short* gB = B + (int64_t)(col0 + bb + lrow) * IN_F + lch * 8;
    const int lbA  = w * 1024;
    const int lbB  = 32768 + bb * 128;

    // ---- 32x32 fragment read addresses ----
    // A-frag(f,c): row = wm*128 + f*32 + (l&31); chunk = 2c + (l>>5);
    // swizzled pos = chunk ^ (row&7) = (2c + (l>>5)) ^ (l&7).
    const int l31 = lane & 31;
    const int hi  = lane >> 5;        // 0/1
    const int m7  = lane & 7;
    int aAddr[4], bAddr[4];
#pragma unroll
    for (int c_ = 0; c_ < 4; ++c_) {
        const int pos = (((2 * c_ + hi) ^ m7) << 4);
        aAddr[c_] = (wm * 128 + l31) * 128 + pos;
        bAddr[c_] = 32768 + (wn * 64 + l31) * 128 + pos;
    }

    floatx16 acc[4][2];
#pragma unroll
    for (int i = 0; i < 4; ++i)
#pragma unroll
        for (int j = 0; j < 2; ++j) acc[i][j] = (floatx16)(0.0f);

    shortx8 af[2][4], bn0[4], bn1[4];

    // prologue: tile0 all 4 units -> buf0; tile1 U0-U2 -> buf1 (14 loads/wave).
    ST_U0(0, 0); ST_U1(0, 0); ST_U2(0, 0); ST_U3(0, 0);
    ST_U0(1, 65536); ST_U1(1, 65536); ST_U2(1, 65536);
    VMC(6);
    BAR();
    RD_AF01(0);   // m01 frags of tile0  (from U0, landed)
    RD_BN0(0);    // n0 frags of tile0   (from U1, landed)

#pragma unroll 1
    for (int it = 0; it < 31; ++it) {            // tiles 0..61; stages reach k-tile 63
        PH1(0, 65536, 1); PH2(0, 2); PH3(0, 65536, 2); PH4(0, 65536, 2);
        PH1(65536, 0, 2); PH2(65536, 3); PH3(65536, 0, 3); PH4(65536, 0, 3);
        gA += 128; gB += 128;                    // advance 2 K-tiles
    }
    // ---- tail: tile 62 (buf0) stages only U3(63); ladder 8/8/4/2/0 as R3/R4 ----
    VMC(8); BAR(); ST_U3(1, 65536); RD_BN1(0); QUAD(0, 0, bn0);      BAR();
    VMC(8); BAR();                  QUAD(0, 1, bn1); RD_AF23(0);     BAR();
    VMC(4); BAR();                  QUAD(2, 0, bn0); RD_BN0(65536);  BAR();
    VMC(2); BAR();                  QUAD(2, 1, bn1); RD_AF01(65536); BAR();
    // ---- tile 63 (buf1): everything landed after VMC(0) ----
    VMC(0); BAR();
    RD_BN1(65536);
    QUAD(0, 0, bn0); QUAD(0, 1, bn1);
    RD_AF23(65536);                              // reg-WAR after QUAD(0,1)
    QUAD(2, 0, bn0); QUAD(2, 1, bn1);

    // epilogue: C/D 32x32 layout col = lane&31, row = (reg&3)+8*(reg>>2)+4*(lane>>5)
#pragma unroll
    for (int nf = 0; nf < 2; ++nf) {
        const int gcol = col0 + wn * 64 + nf * 32 + l31;
        const float bv = bias[gcol];
#pragma unroll
        for (int mf = 0; mf < 4; ++mf) {
            const int rb = row0 + wm * 128 + mf * 32 + 4 * hi;
            float* outp = C + (int64_t)rb * OUT_F + gcol;
#pragma unroll
            for (int r = 0; r < 16; ++r) {
                const int ro = (r & 3) + 8 * (r >> 2);
                outp[(int64_t)ro * OUT_F] = acc[mf][nf][r] + bv;
            }
        }
    }
}

extern "C" void kernel_launch(void* const* d_in, const int* in_sizes, int n_in,
                              void* d_out, int out_size, void* d_ws, size_t ws_size,
                              hipStream_t stream) {
    const float* x    = (const float*)d_in[0];
    const int*   qw   = (const int*)d_in[1];
    const float* sc   = (const float*)d_in[2];
    const float* bias = (const float*)d_in[3];
    float*       out  = (float*)d_out;

    // workspace: [x_bf16: 64 MiB][w_bf16: 32 MiB]
    short* xb = (short*)d_ws;
    short* wb = (short*)((char*)d_ws + (size_t)MROWS * IN_F * sizeof(short));

    preprocess_kernel<<<PRE_XBLK + PRE_WBLK, 256, 0, stream>>>(
        x, xb, qw, sc, wb);

    gemm_bf16_8phase<<<dim3((MROWS / 256) * (OUT_F / 256)), dim3(512), 0, stream>>>(
        xb, wb, bias, out);
}